// Round 1
// baseline (997.833 us; speedup 1.0000x reference)
//
#include <hip/hip_runtime.h>
#include <hip/hip_bf16.h>
#include <cstdint>

typedef __hip_bfloat16 bf16;
typedef _Float16 f16;
typedef f16 f16x2 __attribute__((ext_vector_type(2)));
typedef f16 f16x8 __attribute__((ext_vector_type(8)));
typedef float f32x4 __attribute__((ext_vector_type(4)));

#define C_IN   64
#define C_HID  128
#define C_LAT  32
#define C_H    8
#define C_L    3
#define C_G    64

// Runtime input-dtype handling (harness may hand fp32 or bf16). flag==1 -> fp32.
__device__ inline float load_in(const void* p, size_t idx, int is_f32) {
    if (is_f32) return ((const float*)p)[idx];
    return __bfloat162float(((const bf16*)p)[idx]);
}

__global__ void detect_dtype(const unsigned short* __restrict__ W, int* __restrict__ flag) {
    __shared__ int cnt;
    if (threadIdx.x == 0) cnt = 0;
    __syncthreads();
    int local = 0;
    for (int i = threadIdx.x; i < 8192; i += 256) {
        int e = (W[i] >> 7) & 0xFF;
        if (e >= 135) local++;
    }
    atomicAdd(&cnt, local);
    __syncthreads();
    if (threadIdx.x == 0) *flag = (cnt > 64) ? 1 : 0;
}

// ---------- weight repack -> split fp16 (hi/lo) Bt[n][k], k = i*16 + trig*8 + h ----------
__device__ inline void split16(float v, f16& hi, f16& lo) {
    hi = (f16)v;
    lo = (f16)(v - (float)hi);
}

__global__ void repack_embed(const void* __restrict__ W, f16* __restrict__ Bh, f16* __restrict__ Bl,
                             const int* __restrict__ flagp) {
    const int is_f32 = *flagp;
    int idx = blockIdx.x * blockDim.x + threadIdx.x;
    if (idx >= 2 * C_HID * C_IN * C_H) return;
    int h = idx & 7; int t = idx >> 3;
    int i = t & 63; t >>= 6;
    int o = t & 127; int trig = t >> 7;
    f16 hi, lo; split16(load_in(W, idx, is_f32), hi, lo);
    int k = i * 16 + trig * 8 + h;
    Bh[o * 1024 + k] = hi;
    Bl[o * 1024 + k] = lo;
}

__global__ void repack_mp(const void* __restrict__ W, f16* __restrict__ Bh, f16* __restrict__ Bl,
                          const int* __restrict__ flagp) {
    const int is_f32 = *flagp;
    int idx = blockIdx.x * blockDim.x + threadIdx.x;
    if (idx >= C_L * 2 * C_HID * C_HID * C_H) return;
    int h = idx & 7; int t = idx >> 3;
    int i = t & 127; t >>= 7;
    int o = t & 127; t >>= 7;
    int trig = t & 1; int l = t >> 1;
    f16 hi, lo; split16(load_in(W, idx, is_f32), hi, lo);
    size_t k = (size_t)(l * 128 + o) * 2048 + i * 16 + trig * 8 + h;
    Bh[k] = hi;
    Bl[k] = lo;
}

// readout weights stay fp32 (tiny GEMM)
__global__ void repack_read(const void* __restrict__ W, float* __restrict__ B, const int* __restrict__ flagp) {
    const int is_f32 = *flagp;
    int idx = blockIdx.x * blockDim.x + threadIdx.x;
    if (idx >= 2 * C_LAT * C_HID * C_H) return;
    int h = idx & 7; int t = idx >> 3;
    int i = t & 127; t >>= 7;
    int o = t & 31; int trig = t >> 5;
    B[(i * 16 + trig * 8 + h) * C_LAT + o] = load_in(W, idx, is_f32);
}

// ---------- graph prep ----------
__global__ void deg_count(const int* __restrict__ col, int* __restrict__ deg, int E, int N) {
    int idx = blockIdx.x * blockDim.x + threadIdx.x;
    if (idx >= E + N) return;
    int c = (idx < E) ? col[idx] : (idx - E);
    atomicAdd(&deg[c], 1);
}

__global__ void dinv_kernel(const int* __restrict__ deg, float* __restrict__ dinv, int N) {
    int n = blockIdx.x * blockDim.x + threadIdx.x;
    if (n >= N) return;
    dinv[n] = rsqrtf((float)deg[n]);   // deg >= 1 (self loop)
}

// batch is sorted: gstart[g] = lower_bound(batch, g), g = 0..G (gstart[G] = N)
__global__ void graph_bounds(const int* __restrict__ batch, int* __restrict__ gstart, int N) {
    int g = threadIdx.x;
    if (g > C_G) return;
    int lo = 0, hi = N;
    while (lo < hi) {
        int mid = (lo + hi) >> 1;
        if (batch[mid] < g) lo = mid + 1; else hi = mid;
    }
    gstart[g] = lo;
}

// ---------- hierarchical exclusive scan of deg -> rowptr ----------
__global__ void scan1(const int* __restrict__ deg, int* __restrict__ rowptr,
                      int* __restrict__ bsum, int N) {
    __shared__ int sdata[1024];
    int i = blockIdx.x * 1024 + threadIdx.x;
    int v = (i < N) ? deg[i] : 0;
    sdata[threadIdx.x] = v;
    __syncthreads();
    for (int off = 1; off < 1024; off <<= 1) {
        int t = (threadIdx.x >= (unsigned)off) ? sdata[threadIdx.x - off] : 0;
        __syncthreads();
        sdata[threadIdx.x] += t;
        __syncthreads();
    }
    if (i < N) rowptr[i + 1] = sdata[threadIdx.x];
    if (threadIdx.x == 1023) bsum[blockIdx.x] = sdata[1023];
}

__global__ void scan2(int* __restrict__ bsum, int nb) {
    if (threadIdx.x == 0) {
        int acc = 0;
        for (int i = 0; i < nb; ++i) { int t = bsum[i]; bsum[i] = acc; acc += t; }
    }
}

__global__ void scan3(int* __restrict__ rowptr, const int* __restrict__ bsum, int N) {
    int i = blockIdx.x * 1024 + threadIdx.x;
    if (i < N) rowptr[i + 1] += bsum[blockIdx.x];
    if (i == 0) rowptr[0] = 0;
}

__global__ void csr_fill(const int* __restrict__ row, const int* __restrict__ col,
                         const int* __restrict__ rowptr, int* __restrict__ cursor,
                         int* __restrict__ srcs, int E, int N) {
    int idx = blockIdx.x * blockDim.x + threadIdx.x;
    if (idx >= E + N) return;
    int r, c;
    if (idx < E) { r = row[idx]; c = col[idx]; } else { r = c = idx - E; }
    int pos = rowptr[c] + atomicAdd(&cursor[c], 1);
    srcs[pos] = r;
}

// ---------- Phi split-fp16 generation ----------
// A-tile LDS row stride: 64 data + 8 pad f16 (144 B = bank-group rotation by 4 -> floor)
#define AST 72

__device__ inline void phi_write_split(f16* __restrict__ Ah, f16* __restrict__ Al,
                                       int row, int f, float x) {
    float c[8], s[8];
    __sincosf(x, &s[0], &c[0]);
#pragma unroll
    for (int h = 1; h < 8; ++h) {
        c[h] = c[h-1] * c[0] - s[h-1] * s[0];
        s[h] = s[h-1] * c[0] + c[h-1] * s[0];
    }
    f16x8 ch, cl, sh, sl;
#pragma unroll
    for (int h = 0; h < 8; ++h) {
        f16 hi, lo;
        split16(c[h], hi, lo); ch[h] = hi; cl[h] = lo;
        split16(s[h], hi, lo); sh[h] = hi; sl[h] = lo;
    }
    *(f16x8*)&Ah[row * AST + f * 16]     = ch;
    *(f16x8*)&Ah[row * AST + f * 16 + 8] = sh;
    *(f16x8*)&Al[row * AST + f * 16]     = cl;
    *(f16x8*)&Al[row * AST + f * 16 + 8] = sl;
}

// ---------- split-fp16 MFMA fused-Phi GEMM: Y[M,128] = Phi(X)[M, INF*16] x Bt^T ----------
// v3 structure: K=64 stages, ping-pong A buffer (1 barrier/stage), B direct global->reg
// (L2-resident, no LDS bounce), all 256 threads generate phi for the NEXT stage while
// the current stage's MFMAs run.
template<int INF, bool F16OUT>
__global__ __launch_bounds__(256, 3) void kan_gemm_mfma(const void* __restrict__ X,
                                                        const f16* __restrict__ Bth, const f16* __restrict__ Btl,
                                                        float* __restrict__ Yf, f16* __restrict__ Yh,
                                                        const float* __restrict__ dinv,
                                                        int M, const int* __restrict__ flagp) {
    constexpr int K = INF * 16;
    constexpr int NST = INF / 4;     // stages of K=64 (4 input features each)
    __shared__ f16 AhB[2][64 * AST];
    __shared__ f16 AlB[2][64 * AST];
    __shared__ float dinvs[64];
    const int is_f32 = flagp ? *flagp : 1;
    const int tid  = threadIdx.x;
    const int m0   = blockIdx.x * 64;
    const int w    = tid >> 6, lane = tid & 63;
    const int quad = lane >> 4, l16 = lane & 15;

    // phi role: every thread owns one (row, feature) pair per stage
    const int prow = tid & 63;
    const int pf   = tid >> 6;       // 0..3
    const int gm   = m0 + prow;
    const bool rowok = gm < M;

    if (F16OUT && tid < 64) dinvs[tid] = (m0 + tid < M) ? dinv[m0 + tid] : 0.f;

    f32x4 acc[4][2] = {};

    // B fragment base pointers: row n = w*32 + nt*16 + l16, k offset quad*8
    const f16* bptr0h = Bth + (size_t)(w * 32 + l16) * K + quad * 8;
    const f16* bptr1h = bptr0h + (size_t)16 * K;
    const f16* bptr0l = Btl + (size_t)(w * 32 + l16) * K + quad * 8;
    const f16* bptr1l = bptr0l + (size_t)16 * K;

    // x pipeline: x0 for stage 0 (phi'd pre-loop), xn for stage 1, xf prefetched 2 ahead
    float x0 = rowok ? load_in(X, (size_t)gm * INF + pf, is_f32) : 0.f;
    float xn = (NST > 1 && rowok) ? load_in(X, (size_t)gm * INF + 4 + pf, is_f32) : 0.f;

    phi_write_split(AhB[0], AlB[0], prow, pf, x0);
    __syncthreads();

    int cur = 0;
    for (int s = 0; s < NST; ++s) {
        // B fragments for this stage (global, L2-hit; each block reads B exactly once)
        f16x8 bh[2][2], bl[2][2];
#pragma unroll
        for (int kc = 0; kc < 2; ++kc) {
            const int koff = s * 64 + kc * 32;
            bh[kc][0] = *(const f16x8*)(bptr0h + koff);
            bh[kc][1] = *(const f16x8*)(bptr1h + koff);
            bl[kc][0] = *(const f16x8*)(bptr0l + koff);
            bl[kc][1] = *(const f16x8*)(bptr1l + koff);
        }

        // x prefetch two stages ahead
        float xf = 0.f;
        if (s + 2 < NST && rowok)
            xf = load_in(X, (size_t)gm * INF + (s + 2) * 4 + pf, is_f32);

        // phi for NEXT stage into the other buffer (overlaps this stage's MFMAs)
        if (s + 1 < NST)
            phi_write_split(AhB[cur ^ 1], AlB[cur ^ 1], prow, pf, xn);

        const f16* Ach = AhB[cur];
        const f16* Acl = AlB[cur];
#pragma unroll
        for (int kc = 0; kc < 2; ++kc) {
            f16x8 ah[4], al[4];
#pragma unroll
            for (int mt = 0; mt < 4; ++mt) {
                ah[mt] = *(const f16x8*)&Ach[(mt * 16 + l16) * AST + kc * 32 + quad * 8];
                al[mt] = *(const f16x8*)&Acl[(mt * 16 + l16) * AST + kc * 32 + quad * 8];
            }
            __builtin_amdgcn_s_setprio(1);
#pragma unroll
            for (int mt = 0; mt < 4; ++mt)
#pragma unroll
                for (int nt = 0; nt < 2; ++nt) {
                    acc[mt][nt] = __builtin_amdgcn_mfma_f32_16x16x32_f16(ah[mt], bh[kc][nt], acc[mt][nt], 0, 0, 0);
                    acc[mt][nt] = __builtin_amdgcn_mfma_f32_16x16x32_f16(ah[mt], bl[kc][nt], acc[mt][nt], 0, 0, 0);
                    acc[mt][nt] = __builtin_amdgcn_mfma_f32_16x16x32_f16(al[mt], bh[kc][nt], acc[mt][nt], 0, 0, 0);
                }
            __builtin_amdgcn_s_setprio(0);
        }
        __syncthreads();   // one barrier per stage: next-stage phi written, this-stage reads done
        cur ^= 1;
        xn = xf;
    }

    // C/D layout: col = lane&15, row = quad*4 + reg
#pragma unroll
    for (int mt = 0; mt < 4; ++mt) {
        int rloc = mt * 16 + quad * 4;
#pragma unroll
        for (int nt = 0; nt < 2; ++nt) {
            int cn = w * 32 + nt * 16 + l16;
#pragma unroll
            for (int r = 0; r < 4; ++r) {
                int m = m0 + rloc + r;
                if (m < M) {
                    if (F16OUT) Yh[(size_t)m * 128 + cn] = (f16)(acc[mt][nt][r] * dinvs[rloc + r]);
                    else        Yf[(size_t)m * 128 + cn] = acc[mt][nt][r];
                }
            }
        }
    }
}

// ---------- CSR aggregation v2: one wave per dest, shuffled src staging + 4-deep gather ----------
__global__ __launch_bounds__(256) void aggregate(const f16* __restrict__ Hin, float* __restrict__ Hout,
                                                 const int* __restrict__ rowptr, const int* __restrict__ srcs,
                                                 const float* __restrict__ dinv, int N) {
    int wave = (int)((blockIdx.x * blockDim.x + threadIdx.x) >> 6);
    int lane = threadIdx.x & 63;
    if (wave >= N) return;
    const f16x2* H2 = (const f16x2*)Hin;
    int beg = rowptr[wave], end = rowptr[wave + 1];
    float2 a0 = {0.f, 0.f}, a1 = {0.f, 0.f};
    int j = beg;
    while (j < end) {
        int cnt = end - j; if (cnt > 64) cnt = 64;
        // one coalesced load stages up to 64 edge IDs across the wave
        int sv = (lane < cnt) ? srcs[j + lane] : 0;
        int t = 0;
        for (; t + 4 <= cnt; t += 4) {
            int s0 = __shfl(sv, t + 0);
            int s1 = __shfl(sv, t + 1);
            int s2 = __shfl(sv, t + 2);
            int s3 = __shfl(sv, t + 3);
            // 4 independent row-gathers in flight
            f16x2 h0 = H2[(size_t)s0 * 64 + lane];
            f16x2 h1 = H2[(size_t)s1 * 64 + lane];
            f16x2 h2 = H2[(size_t)s2 * 64 + lane];
            f16x2 h3 = H2[(size_t)s3 * 64 + lane];
            a0.x += (float)h0[0] + (float)h1[0];
            a0.y += (float)h0[1] + (float)h1[1];
            a1.x += (float)h2[0] + (float)h3[0];
            a1.y += (float)h2[1] + (float)h3[1];
        }
        for (; t < cnt; ++t) {
            int s0 = __shfl(sv, t);
            f16x2 h0 = H2[(size_t)s0 * 64 + lane];
            a0.x += (float)h0[0];
            a0.y += (float)h0[1];
        }
        j += cnt;
    }
    float dv = dinv[wave];
    float2 acc = {(a0.x + a1.x) * dv, (a0.y + a1.y) * dv};
    ((float2*)Hout)[(size_t)wave * 64 + lane] = acc;
}

// ---------- fused mean-pool + readout: block g sums rows [gstart[g], gstart[g+1]) ----------
__global__ __launch_bounds__(256) void pool_readout(const float* __restrict__ H, const int* __restrict__ gstart,
                                                    const float* __restrict__ B, void* __restrict__ out,
                                                    const int* __restrict__ flagp) {
    __shared__ float phi[2048];
    __shared__ float red[256];
    __shared__ float part[8][32];
    const int is_f32 = *flagp;
    int g = blockIdx.x;
    int tid = threadIdx.x;
    int s0 = gstart[g], e0 = gstart[g + 1];
    int f = tid & 127, half = tid >> 7;
    float sum = 0.f;
    for (int n = s0 + half; n < e0; n += 2)
        sum += H[(size_t)n * C_HID + f];
    red[tid] = sum;
    __syncthreads();
    if (tid < 128) {
        float cnt = fmaxf((float)(e0 - s0), 1.0f);
        float x = (red[tid] + red[tid + 128]) / cnt;
        float s1, c1;
        __sincosf(x, &s1, &c1);
        phi[tid * 16 + 0] = c1; phi[tid * 16 + 8] = s1;
        float ck = c1, sk = s1;
#pragma unroll
        for (int h = 1; h < 8; ++h) {
            float cn = ck * c1 - sk * s1;
            float sn = sk * c1 + ck * s1;
            phi[tid * 16 + h] = cn; phi[tid * 16 + 8 + h] = sn;
            ck = cn; sk = sn;
        }
    }
    __syncthreads();
    int o = tid & 31, p = tid >> 5;
    float acc = 0.f;
    for (int k = p * 256; k < p * 256 + 256; ++k)
        acc = fmaf(phi[k], B[k * C_LAT + o], acc);
    part[p][o] = acc;
    __syncthreads();
    if (tid < 32) {
        float s = 0.f;
#pragma unroll
        for (int pp = 0; pp < 8; ++pp) s += part[pp][tid];
        if (is_f32) ((float*)out)[g * C_LAT + tid] = s;
        else        ((bf16*)out)[g * C_LAT + tid] = __float2bfloat16(s);
    }
}

extern "C" void kernel_launch(void* const* d_in, const int* in_sizes, int n_in,
                              void* d_out, int out_size, void* d_ws, size_t ws_size,
                              hipStream_t stream) {
    const void* features = d_in[0];
    const int*  edge     = (const int*)d_in[1];
    const int*  batch    = (const int*)d_in[2];
    const void* W_embed  = d_in[3];
    const void* W_mp     = d_in[4];
    const void* W_read   = d_in[5];

    const int N = in_sizes[0] / C_IN;
    const int E = in_sizes[1] / 2;
    const int* row = edge;
    const int* col = edge + E;
    const int nScanBlocks = (N + 1023) / 1024;

    char* ws = (char*)d_ws;
    auto alloc = [&](size_t bytes) { char* p = ws; ws += (bytes + 255) & ~(size_t)255; return p; };
    float* h_a    = (float*)alloc((size_t)N * C_HID * 4);
    f16*   h16    = (f16*)alloc((size_t)N * C_HID * 2);
    f16*   BteH   = (f16*)alloc((size_t)C_HID * 1024 * 2);
    f16*   BteL   = (f16*)alloc((size_t)C_HID * 1024 * 2);
    f16*   BtmpH  = (f16*)alloc((size_t)C_L * C_HID * 2048 * 2);
    f16*   BtmpL  = (f16*)alloc((size_t)C_L * C_HID * 2048 * 2);
    float* Brd    = (float*)alloc((size_t)2048 * C_LAT * 4);
    int*   deg    = (int*)alloc((size_t)N * 4);
    float* dinv   = (float*)alloc((size_t)N * 4);
    int*   rowptr = (int*)alloc((size_t)(N + 1) * 4);
    int*   cursor = (int*)alloc((size_t)N * 4);
    int*   srcs   = (int*)alloc((size_t)(E + N) * 4);
    int*   bsum   = (int*)alloc((size_t)nScanBlocks * 4);
    int*   gstart = (int*)alloc((size_t)(C_G + 1) * 4);
    int*   dflag  = (int*)alloc(256);

    hipMemsetAsync(deg, 0, (size_t)N * 4, stream);
    hipMemsetAsync(cursor, 0, (size_t)N * 4, stream);

    detect_dtype<<<1, 256, 0, stream>>>((const unsigned short*)W_embed, dflag);

    repack_embed<<<(2 * C_HID * C_IN * C_H + 255) / 256, 256, 0, stream>>>(W_embed, BteH, BteL, dflag);
    repack_mp<<<(C_L * 2 * C_HID * C_HID * C_H + 255) / 256, 256, 0, stream>>>(W_mp, BtmpH, BtmpL, dflag);
    repack_read<<<(2 * C_LAT * C_HID * C_H + 255) / 256, 256, 0, stream>>>(W_read, Brd, dflag);

    deg_count<<<(E + N + 255) / 256, 256, 0, stream>>>(col, deg, E, N);
    dinv_kernel<<<(N + 255) / 256, 256, 0, stream>>>(deg, dinv, N);
    graph_bounds<<<1, 128, 0, stream>>>(batch, gstart, N);
    scan1<<<nScanBlocks, 1024, 0, stream>>>(deg, rowptr, bsum, N);
    scan2<<<1, 64, 0, stream>>>(bsum, nScanBlocks);
    scan3<<<nScanBlocks, 1024, 0, stream>>>(rowptr, bsum, N);
    csr_fill<<<(E + N + 255) / 256, 256, 0, stream>>>(row, col, rowptr, cursor, srcs, E, N);

    const int gemm_grid = (N + 63) / 64;
    kan_gemm_mfma<C_IN, false><<<gemm_grid, 256, 0, stream>>>(features, BteH, BteL, h_a, nullptr, nullptr, N, dflag);
    for (int l = 0; l < C_L; ++l) {
        kan_gemm_mfma<C_HID, true><<<gemm_grid, 256, 0, stream>>>(h_a, BtmpH + (size_t)l * C_HID * 2048,
                                                                  BtmpL + (size_t)l * C_HID * 2048,
                                                                  nullptr, h16, dinv, N, nullptr);
        aggregate<<<((size_t)N * 64 + 255) / 256, 256, 0, stream>>>(h16, h_a, rowptr, srcs, dinv, N);
    }

    pool_readout<<<C_G, 256, 0, stream>>>(h_a, gstart, Brd, d_out, dflag);
}

// Round 3
// 894.316 us; speedup vs baseline: 1.1158x; 1.1158x over previous
//
#include <hip/hip_runtime.h>
#include <hip/hip_bf16.h>
#include <cstdint>

typedef __hip_bfloat16 bf16;
typedef _Float16 f16;
typedef f16 f16x2 __attribute__((ext_vector_type(2)));
typedef f16 f16x8 __attribute__((ext_vector_type(8)));
typedef float f32x4 __attribute__((ext_vector_type(4)));

#define C_IN   64
#define C_HID  128
#define C_LAT  32
#define C_H    8
#define C_L    3
#define C_G    64

// Runtime input-dtype handling (harness may hand fp32 or bf16). flag==1 -> fp32.
__device__ inline float load_in(const void* p, size_t idx, int is_f32) {
    if (is_f32) return ((const float*)p)[idx];
    return __bfloat162float(((const bf16*)p)[idx]);
}

__global__ void detect_dtype(const unsigned short* __restrict__ W, int* __restrict__ flag) {
    __shared__ int cnt;
    if (threadIdx.x == 0) cnt = 0;
    __syncthreads();
    int local = 0;
    for (int i = threadIdx.x; i < 8192; i += 256) {
        int e = (W[i] >> 7) & 0xFF;
        if (e >= 135) local++;
    }
    atomicAdd(&cnt, local);
    __syncthreads();
    if (threadIdx.x == 0) *flag = (cnt > 64) ? 1 : 0;
}

__device__ inline void split16(float v, f16& hi, f16& lo) {
    hi = (f16)v;
    lo = (f16)(v - (float)hi);
}

// ---------- weight repack -> fragment-major split-f16 layout ----------
// B[((s*8 + j)*256 + t)*8 + e], j = kc*4 + hl*2 + nt
// frag(j,t): o = w*32 + nt*16 + l16;  kglob = s*64 + kc*32 + quad*8 + e
// A wave's 64 lanes load frag j contiguously (16 B/lane, 1 KB/instr): perfect coalescing.
__global__ void repack_embed(const void* __restrict__ W, f16* __restrict__ B,
                             const int* __restrict__ flagp) {
    const int is_f32 = *flagp;
    int idx = blockIdx.x * blockDim.x + threadIdx.x;
    if (idx >= 16 * 8 * 256 * 8) return;          // 262144 f16
    int e = idx & 7;
    int t = (idx >> 3) & 255;
    int j = (idx >> 11) & 7;
    int s = (idx >> 14) & 15;
    int w = t >> 6, lane = t & 63, quad = lane >> 4, l16 = lane & 15;
    int kc = j >> 2, hl = (j >> 1) & 1, nt = j & 1;
    int o  = w * 32 + nt * 16 + l16;
    int kg = s * 64 + kc * 32 + quad * 8 + e;
    int i = kg >> 4, trig = (kg >> 3) & 1, h = kg & 7;
    int widx = ((trig * C_HID + o) * C_IN + i) * C_H + h;
    f16 hi, lo; split16(load_in(W, widx, is_f32), hi, lo);
    B[idx] = hl ? lo : hi;
}

__global__ void repack_mp(const void* __restrict__ W, f16* __restrict__ B,
                          const int* __restrict__ flagp) {
    const int is_f32 = *flagp;
    int idx = blockIdx.x * blockDim.x + threadIdx.x;
    if (idx >= C_L * 32 * 8 * 256 * 8) return;    // 1572864 f16
    int e = idx & 7;
    int t = (idx >> 3) & 255;
    int j = (idx >> 11) & 7;
    int s = (idx >> 14) & 31;
    int l = idx >> 19;
    int w = t >> 6, lane = t & 63, quad = lane >> 4, l16 = lane & 15;
    int kc = j >> 2, hl = (j >> 1) & 1, nt = j & 1;
    int o  = w * 32 + nt * 16 + l16;
    int kg = s * 64 + kc * 32 + quad * 8 + e;
    int i = kg >> 4, trig = (kg >> 3) & 1, h = kg & 7;
    int widx = (((l * 2 + trig) * C_HID + o) * C_HID + i) * C_H + h;
    f16 hi, lo; split16(load_in(W, widx, is_f32), hi, lo);
    B[idx] = hl ? lo : hi;
}

// readout weights stay fp32 (tiny GEMM)
__global__ void repack_read(const void* __restrict__ W, float* __restrict__ B, const int* __restrict__ flagp) {
    const int is_f32 = *flagp;
    int idx = blockIdx.x * blockDim.x + threadIdx.x;
    if (idx >= 2 * C_LAT * C_HID * C_H) return;
    int h = idx & 7; int t = idx >> 3;
    int i = t & 127; t >>= 7;
    int o = t & 31; int trig = t >> 5;
    B[(i * 16 + trig * 8 + h) * C_LAT + o] = load_in(W, idx, is_f32);
}

// ---------- graph prep ----------
__global__ void deg_count(const int* __restrict__ col, int* __restrict__ deg, int E, int N) {
    int idx = blockIdx.x * blockDim.x + threadIdx.x;
    if (idx >= E + N) return;
    int c = (idx < E) ? col[idx] : (idx - E);
    atomicAdd(&deg[c], 1);
}

__global__ void dinv_kernel(const int* __restrict__ deg, float* __restrict__ dinv, int N) {
    int n = blockIdx.x * blockDim.x + threadIdx.x;
    if (n >= N) return;
    dinv[n] = rsqrtf((float)deg[n]);   // deg >= 1 (self loop)
}

__global__ void graph_bounds(const int* __restrict__ batch, int* __restrict__ gstart, int N) {
    int g = threadIdx.x;
    if (g > C_G) return;
    int lo = 0, hi = N;
    while (lo < hi) {
        int mid = (lo + hi) >> 1;
        if (batch[mid] < g) lo = mid + 1; else hi = mid;
    }
    gstart[g] = lo;
}

// ---------- hierarchical exclusive scan of deg -> rowptr ----------
__global__ void scan1(const int* __restrict__ deg, int* __restrict__ rowptr,
                      int* __restrict__ bsum, int N) {
    __shared__ int sdata[1024];
    int i = blockIdx.x * 1024 + threadIdx.x;
    int v = (i < N) ? deg[i] : 0;
    sdata[threadIdx.x] = v;
    __syncthreads();
    for (int off = 1; off < 1024; off <<= 1) {
        int t = (threadIdx.x >= (unsigned)off) ? sdata[threadIdx.x - off] : 0;
        __syncthreads();
        sdata[threadIdx.x] += t;
        __syncthreads();
    }
    if (i < N) rowptr[i + 1] = sdata[threadIdx.x];
    if (threadIdx.x == 1023) bsum[blockIdx.x] = sdata[1023];
}

__global__ void scan2(int* __restrict__ bsum, int nb) {
    if (threadIdx.x == 0) {
        int acc = 0;
        for (int i = 0; i < nb; ++i) { int t = bsum[i]; bsum[i] = acc; acc += t; }
    }
}

__global__ void scan3(int* __restrict__ rowptr, const int* __restrict__ bsum, int N) {
    int i = blockIdx.x * 1024 + threadIdx.x;
    if (i < N) rowptr[i + 1] += bsum[blockIdx.x];
    if (i == 0) rowptr[0] = 0;
}

__global__ void csr_fill(const int* __restrict__ row, const int* __restrict__ col,
                         const int* __restrict__ rowptr, int* __restrict__ cursor,
                         int* __restrict__ srcs, int E, int N) {
    int idx = blockIdx.x * blockDim.x + threadIdx.x;
    if (idx >= E + N) return;
    int r, c;
    if (idx < E) { r = row[idx]; c = col[idx]; } else { r = c = idx - E; }
    int pos = rowptr[c] + atomicAdd(&cursor[c], 1);
    srcs[pos] = r;
}

// ---------- Phi split-fp16 generation into XOR-swizzled [64][64] A-tile ----------
// Row stride 64 f16 (128 B, no pad). 16-B chunk c of row r lives at chunk (c ^ (r&7)).
// Writes: 64 lanes x rows 0..63, chunk (w*2+trig)^(lane&7) -> exactly 8 dwords/bank (min).
// Reads:  frag (row=mt*16+l16, chunk=kc*4+quad)^(l16&7)   -> exactly 8 dwords/bank (min).
__device__ inline void phi_write_split(f16* __restrict__ Ah, f16* __restrict__ Al,
                                       int offC, int offS, float x) {
    float c[8], s[8];
    __sincosf(x, &s[0], &c[0]);
#pragma unroll
    for (int h = 1; h < 8; ++h) {
        c[h] = c[h-1] * c[0] - s[h-1] * s[0];
        s[h] = s[h-1] * c[0] + c[h-1] * s[0];
    }
    f16x8 ch, cl, sh, sl;
#pragma unroll
    for (int h = 0; h < 8; ++h) {
        f16 hi, lo;
        split16(c[h], hi, lo); ch[h] = hi; cl[h] = lo;
        split16(s[h], hi, lo); sh[h] = hi; sl[h] = lo;
    }
    *(f16x8*)&Ah[offC] = ch;
    *(f16x8*)&Ah[offS] = sh;
    *(f16x8*)&Al[offC] = cl;
    *(f16x8*)&Al[offS] = sl;
}

// ---------- split-fp16 MFMA fused-Phi GEMM: Y[M,128] = Phi(X)[M, INF*16] x Bt^T ----------
// v4 (resubmit; round-2 run died to infra before launch): K=64 stages, 1 barrier/stage,
// A ping-pong in swizzled LDS, B double-buffered in REGISTERS from fragment-major global
// layout (coalesced 16B/lane, L2-resident), phi(next) + B(next) overlap current MFMAs.
#define STAGE_BODY(S, BC, BN, ACUR_H, ACUR_L, ANXT_H, ANXT_L)                         \
  {                                                                                    \
    const int s_ = (S);                                                                \
    if (s_ + 1 < NST) {                                                                \
      _Pragma("unroll")                                                                \
      for (int j = 0; j < 8; ++j)                                                      \
        BN[j] = Bf[((size_t)(s_ + 1) * 8 + j) * 256 + tid];                            \
    }                                                                                  \
    float xf_ = 0.f;                                                                   \
    if (s_ + 2 < NST && rowok)                                                         \
      xf_ = load_in(X, (size_t)gm * INF + (s_ + 2) * 4 + pf, is_f32);                  \
    if (s_ + 1 < NST)                                                                  \
      phi_write_split(ANXT_H, ANXT_L, offC, offS, xn);                                 \
    _Pragma("unroll")                                                                  \
    for (int kc = 0; kc < 2; ++kc) {                                                   \
      f16x8 ah[4], al[4];                                                              \
      _Pragma("unroll")                                                                \
      for (int mt = 0; mt < 4; ++mt) {                                                 \
        int ro = (mt * 16 + l16) * 64 + (((kc * 4 + quad) ^ (l16 & 7)) * 8);           \
        ah[mt] = *(const f16x8*)&ACUR_H[ro];                                           \
        al[mt] = *(const f16x8*)&ACUR_L[ro];                                           \
      }                                                                                \
      __builtin_amdgcn_s_setprio(1);                                                   \
      _Pragma("unroll")                                                                \
      for (int mt = 0; mt < 4; ++mt)                                                   \
        _Pragma("unroll")                                                              \
        for (int nt = 0; nt < 2; ++nt) {                                               \
          acc[mt][nt] = __builtin_amdgcn_mfma_f32_16x16x32_f16(ah[mt], BC[kc*4+nt],   acc[mt][nt], 0, 0, 0); \
          acc[mt][nt] = __builtin_amdgcn_mfma_f32_16x16x32_f16(ah[mt], BC[kc*4+2+nt], acc[mt][nt], 0, 0, 0); \
          acc[mt][nt] = __builtin_amdgcn_mfma_f32_16x16x32_f16(al[mt], BC[kc*4+nt],   acc[mt][nt], 0, 0, 0); \
        }                                                                              \
      __builtin_amdgcn_s_setprio(0);                                                   \
    }                                                                                  \
    __syncthreads();                                                                   \
    xn = xf_;                                                                          \
  }

template<int INF, bool F16OUT>
__global__ __launch_bounds__(256, 3) void kan_gemm_mfma(const void* __restrict__ X,
                                                        const f16* __restrict__ Bt,
                                                        float* __restrict__ Yf, f16* __restrict__ Yh,
                                                        const float* __restrict__ dinv,
                                                        int M, const int* __restrict__ flagp) {
    constexpr int NST = INF / 4;     // stages of K=64 (4 input features each)
    __shared__ f16 AhB[2][64 * 64];
    __shared__ f16 AlB[2][64 * 64];
    __shared__ float dinvs[64];
    const int is_f32 = flagp ? *flagp : 1;
    const int tid  = threadIdx.x;
    const int m0   = blockIdx.x * 64;
    const int w    = tid >> 6, lane = tid & 63;
    const int quad = lane >> 4, l16 = lane & 15;

    // phi role: thread owns (row = lane, feature = w) each stage
    const int pf   = w;
    const int gm   = m0 + lane;
    const bool rowok = gm < M;
    const int offC = lane * 64 + (((w * 2)     ^ (lane & 7)) * 8);
    const int offS = lane * 64 + (((w * 2 + 1) ^ (lane & 7)) * 8);

    if (F16OUT && tid < 64) dinvs[tid] = (m0 + tid < M) ? dinv[m0 + tid] : 0.f;

    f32x4 acc[4][2] = {};
    const f16x8* __restrict__ Bf = (const f16x8*)Bt;

    f16x8 b0[8], b1[8];
#pragma unroll
    for (int j = 0; j < 8; ++j) b0[j] = Bf[(size_t)j * 256 + tid];

    float x0 = rowok ? load_in(X, (size_t)gm * INF + pf, is_f32) : 0.f;
    float xn = (NST > 1 && rowok) ? load_in(X, (size_t)gm * INF + 4 + pf, is_f32) : 0.f;

    phi_write_split(AhB[0], AlB[0], offC, offS, x0);
    __syncthreads();

    for (int s = 0; s < NST; s += 2) {
        STAGE_BODY(s,     b0, b1, AhB[0], AlB[0], AhB[1], AlB[1]);
        STAGE_BODY(s + 1, b1, b0, AhB[1], AlB[1], AhB[0], AlB[0]);
    }

    // C/D layout: col = lane&15, row = quad*4 + reg
#pragma unroll
    for (int mt = 0; mt < 4; ++mt) {
        int rloc = mt * 16 + quad * 4;
#pragma unroll
        for (int nt = 0; nt < 2; ++nt) {
            int cn = w * 32 + nt * 16 + l16;
#pragma unroll
            for (int r = 0; r < 4; ++r) {
                int m = m0 + rloc + r;
                if (m < M) {
                    if (F16OUT) Yh[(size_t)m * 128 + cn] = (f16)(acc[mt][nt][r] * dinvs[rloc + r]);
                    else        Yf[(size_t)m * 128 + cn] = acc[mt][nt][r];
                }
            }
        }
    }
}

// ---------- CSR aggregation: one wave per dest, shuffled src staging + 4-deep gather ----------
__global__ __launch_bounds__(256) void aggregate(const f16* __restrict__ Hin, float* __restrict__ Hout,
                                                 const int* __restrict__ rowptr, const int* __restrict__ srcs,
                                                 const float* __restrict__ dinv, int N) {
    int wave = (int)((blockIdx.x * blockDim.x + threadIdx.x) >> 6);
    int lane = threadIdx.x & 63;
    if (wave >= N) return;
    const f16x2* H2 = (const f16x2*)Hin;
    int beg = rowptr[wave], end = rowptr[wave + 1];
    float2 a0 = {0.f, 0.f}, a1 = {0.f, 0.f};
    int j = beg;
    while (j < end) {
        int cnt = end - j; if (cnt > 64) cnt = 64;
        int sv = (lane < cnt) ? srcs[j + lane] : 0;
        int t = 0;
        for (; t + 4 <= cnt; t += 4) {
            int s0 = __shfl(sv, t + 0);
            int s1 = __shfl(sv, t + 1);
            int s2 = __shfl(sv, t + 2);
            int s3 = __shfl(sv, t + 3);
            f16x2 h0 = H2[(size_t)s0 * 64 + lane];
            f16x2 h1 = H2[(size_t)s1 * 64 + lane];
            f16x2 h2 = H2[(size_t)s2 * 64 + lane];
            f16x2 h3 = H2[(size_t)s3 * 64 + lane];
            a0.x += (float)h0[0] + (float)h1[0];
            a0.y += (float)h0[1] + (float)h1[1];
            a1.x += (float)h2[0] + (float)h3[0];
            a1.y += (float)h2[1] + (float)h3[1];
        }
        for (; t < cnt; ++t) {
            int s0 = __shfl(sv, t);
            f16x2 h0 = H2[(size_t)s0 * 64 + lane];
            a0.x += (float)h0[0];
            a0.y += (float)h0[1];
        }
        j += cnt;
    }
    float dv = dinv[wave];
    float2 acc = {(a0.x + a1.x) * dv, (a0.y + a1.y) * dv};
    ((float2*)Hout)[(size_t)wave * 64 + lane] = acc;
}

// ---------- fused mean-pool + readout ----------
__global__ __launch_bounds__(256) void pool_readout(const float* __restrict__ H, const int* __restrict__ gstart,
                                                    const float* __restrict__ B, void* __restrict__ out,
                                                    const int* __restrict__ flagp) {
    __shared__ float phi[2048];
    __shared__ float red[256];
    __shared__ float part[8][32];
    const int is_f32 = *flagp;
    int g = blockIdx.x;
    int tid = threadIdx.x;
    int s0 = gstart[g], e0 = gstart[g + 1];
    int f = tid & 127, half = tid >> 7;
    float sum = 0.f;
    for (int n = s0 + half; n < e0; n += 2)
        sum += H[(size_t)n * C_HID + f];
    red[tid] = sum;
    __syncthreads();
    if (tid < 128) {
        float cnt = fmaxf((float)(e0 - s0), 1.0f);
        float x = (red[tid] + red[tid + 128]) / cnt;
        float s1, c1;
        __sincosf(x, &s1, &c1);
        phi[tid * 16 + 0] = c1; phi[tid * 16 + 8] = s1;
        float ck = c1, sk = s1;
#pragma unroll
        for (int h = 1; h < 8; ++h) {
            float cn = ck * c1 - sk * s1;
            float sn = sk * c1 + ck * s1;
            phi[tid * 16 + h] = cn; phi[tid * 16 + 8 + h] = sn;
            ck = cn; sk = sn;
        }
    }
    __syncthreads();
    int o = tid & 31, p = tid >> 5;
    float acc = 0.f;
    for (int k = p * 256; k < p * 256 + 256; ++k)
        acc = fmaf(phi[k], B[k * C_LAT + o], acc);
    part[p][o] = acc;
    __syncthreads();
    if (tid < 32) {
        float s = 0.f;
#pragma unroll
        for (int pp = 0; pp < 8; ++pp) s += part[pp][tid];
        if (is_f32) ((float*)out)[g * C_LAT + tid] = s;
        else        ((bf16*)out)[g * C_LAT + tid] = __float2bfloat16(s);
    }
}

extern "C" void kernel_launch(void* const* d_in, const int* in_sizes, int n_in,
                              void* d_out, int out_size, void* d_ws, size_t ws_size,
                              hipStream_t stream) {
    const void* features = d_in[0];
    const int*  edge     = (const int*)d_in[1];
    const int*  batch    = (const int*)d_in[2];
    const void* W_embed  = d_in[3];
    const void* W_mp     = d_in[4];
    const void* W_read   = d_in[5];

    const int N = in_sizes[0] / C_IN;
    const int E = in_sizes[1] / 2;
    const int* row = edge;
    const int* col = edge + E;
    const int nScanBlocks = (N + 1023) / 1024;

    char* ws = (char*)d_ws;
    auto alloc = [&](size_t bytes) { char* p = ws; ws += (bytes + 255) & ~(size_t)255; return p; };
    float* h_a    = (float*)alloc((size_t)N * C_HID * 4);
    f16*   h16    = (f16*)alloc((size_t)N * C_HID * 2);
    f16*   Bte    = (f16*)alloc((size_t)16 * 8 * 256 * 8 * 2);          // 512 KB
    f16*   Btmp   = (f16*)alloc((size_t)C_L * 32 * 8 * 256 * 8 * 2);    // 3 MB
    float* Brd    = (float*)alloc((size_t)2048 * C_LAT * 4);
    int*   deg    = (int*)alloc((size_t)N * 4);
    float* dinv   = (float*)alloc((size_t)N * 4);
    int*   rowptr = (int*)alloc((size_t)(N + 1) * 4);
    int*   cursor = (int*)alloc((size_t)N * 4);
    int*   srcs   = (int*)alloc((size_t)(E + N) * 4);
    int*   bsum   = (int*)alloc((size_t)nScanBlocks * 4);
    int*   gstart = (int*)alloc((size_t)(C_G + 1) * 4);
    int*   dflag  = (int*)alloc(256);

    hipMemsetAsync(deg, 0, (size_t)N * 4, stream);
    hipMemsetAsync(cursor, 0, (size_t)N * 4, stream);

    detect_dtype<<<1, 256, 0, stream>>>((const unsigned short*)W_embed, dflag);

    repack_embed<<<(16 * 8 * 256 * 8 + 255) / 256, 256, 0, stream>>>(W_embed, Bte, dflag);
    repack_mp<<<(C_L * 32 * 8 * 256 * 8 + 255) / 256, 256, 0, stream>>>(W_mp, Btmp, dflag);
    repack_read<<<(2 * C_LAT * C_HID * C_H + 255) / 256, 256, 0, stream>>>(W_read, Brd, dflag);

    deg_count<<<(E + N + 255) / 256, 256, 0, stream>>>(col, deg, E, N);
    dinv_kernel<<<(N + 255) / 256, 256, 0, stream>>>(deg, dinv, N);
    graph_bounds<<<1, 128, 0, stream>>>(batch, gstart, N);
    scan1<<<nScanBlocks, 1024, 0, stream>>>(deg, rowptr, bsum, N);
    scan2<<<1, 64, 0, stream>>>(bsum, nScanBlocks);
    scan3<<<nScanBlocks, 1024, 0, stream>>>(rowptr, bsum, N);
    csr_fill<<<(E + N + 255) / 256, 256, 0, stream>>>(row, col, rowptr, cursor, srcs, E, N);

    const int gemm_grid = (N + 63) / 64;
    kan_gemm_mfma<C_IN, false><<<gemm_grid, 256, 0, stream>>>(features, Bte, h_a, nullptr, nullptr, N, dflag);
    for (int l = 0; l < C_L; ++l) {
        kan_gemm_mfma<C_HID, true><<<gemm_grid, 256, 0, stream>>>(h_a, Btmp + (size_t)l * 32 * 8 * 256 * 8,
                                                                  nullptr, h16, dinv, N, nullptr);
        aggregate<<<((size_t)N * 64 + 255) / 256, 256, 0, stream>>>(h16, h_a, rowptr, srcs, dinv, N);
    }

    pool_readout<<<C_G, 256, 0, stream>>>(h_a, gstart, Brd, d_out, dflag);
}